// Round 4
// baseline (25608.307 us; speedup 1.0000x reference)
//
#include <hip/hip_runtime.h>

// QINCo fp32, round 4: lane=row / wave=column-block k_step.
// Per d-iter per wave: 1 ds_read_b128 (bank-optimal) + 16 broadcast global
// weight loads + 64 v_fma. LDS instruction count cut ~16x vs round 3.
// Shapes: D=128, M=8, K=256, L=2, H=256, BS=1024. All fp32.
// Out layout (floats): xhat[1024*128] | codes[1024*8] | side[8][1024*128]

#define OUT_CODES 131072
#define OUT_SIDE  139264

// ws float offsets
#define WS_XHAT  0          // [1024][128]
#define WS_RB    131072     // [1024][128]  r = x - xhat
#define WS_Y     262144     // [1024][128]  y = xhat @ Wx^T
#define WS_ZC    393216     // [256][128]   zc = cb + cb@Wz^T + bc
#define WS_BESTD 425984     // [1024][4]
#define WS_BESTI 430080     // [1024][4] (int)
#define WS_BESTZ 434176     // [1024][4][128]

// Logical element d of row r lives at physical column (d + (r&7)*4) & 127.
__device__ __forceinline__ int rotZ(int r, int d) {
  return (r << 7) + ((d + ((r & 7) << 2)) & 127);
}

// ---------------- step 0: nearest codebook0 row ----------------
__global__ __launch_bounds__(256) void k_step0(const float* __restrict__ x,
    const float* __restrict__ cb0, float* __restrict__ ws, float* __restrict__ out)
{
  __shared__ float xs[128];
  __shared__ float redv[4];
  __shared__ int   redi[4];
  __shared__ int   kwin;
  int tx = threadIdx.x, b = blockIdx.x;
  if (tx < 128) xs[tx] = x[b * 128 + tx];
  __syncthreads();
  const float* c = cb0 + tx * 128;   // k = tx
  float s = 0.f;
  for (int d = 0; d < 128; d += 4) {
    float4 cv = *(const float4*)(c + d);
    float4 xv = *(const float4*)(xs + d);
    float a0 = xv.x - cv.x, a1 = xv.y - cv.y, a2 = xv.z - cv.z, a3 = xv.w - cv.w;
    s += a0 * a0 + a1 * a1 + a2 * a2 + a3 * a3;
  }
  float v = s; int idx = tx;
  for (int off = 32; off; off >>= 1) {
    float v2 = __shfl_xor(v, off);
    int   i2 = __shfl_xor(idx, off);
    if (v2 < v || (v2 == v && i2 < idx)) { v = v2; idx = i2; }
  }
  if ((tx & 63) == 0) { redv[tx >> 6] = v; redi[tx >> 6] = idx; }
  __syncthreads();
  if (tx == 0) {
    float bv = redv[0]; int bi = redi[0];
    for (int w = 1; w < 4; w++)
      if (redv[w] < bv || (redv[w] == bv && redi[w] < bi)) { bv = redv[w]; bi = redi[w]; }
    kwin = bi;
    out[OUT_CODES + b * 8] = (float)bi;
  }
  __syncthreads();
  int k = kwin;
  if (tx < 128) {
    float xh = cb0[k * 128 + tx];
    ws[WS_XHAT + b * 128 + tx] = xh;
    ws[WS_RB   + b * 128 + tx] = xs[tx] - xh;
    out[OUT_SIDE + b * 128 + tx] = xh;   // side[0]
  }
}

// ---------------- per-step prep: zc and y ----------------
__global__ __launch_bounds__(128) void k_prep(const float* __restrict__ cb,
    const float* __restrict__ Wc, const float* __restrict__ bcm, float* __restrict__ ws)
{
  __shared__ float row[128];
  int tx = threadIdx.x, blk = blockIdx.x;
  if (blk < 256) {          // zc[k][i] = cb[k][i] + sum_d cb[k][d]*Wc[i][d] + bc[i]
    row[tx] = cb[blk * 128 + tx];
    __syncthreads();
    const float* wrow = Wc + tx * 256;
    float s = 0.f;
    for (int d = 0; d < 128; d += 4) {
      float4 wv = *(const float4*)(wrow + d);
      float4 zv = *(const float4*)(row + d);
      s += wv.x * zv.x + wv.y * zv.y + wv.z * zv.z + wv.w * zv.w;
    }
    ws[WS_ZC + blk * 128 + tx] = row[tx] + s + bcm[tx];
  } else {                  // y[b][i] = sum_d xhat[b][d]*Wc[i][128+d]
    int b = blk - 256;
    row[tx] = ws[WS_XHAT + b * 128 + tx];
    __syncthreads();
    const float* wrow = Wc + tx * 256 + 128;
    float s = 0.f;
    for (int d = 0; d < 128; d += 4) {
      float4 wv = *(const float4*)(wrow + d);
      float4 zv = *(const float4*)(row + d);
      s += wv.x * zv.x + wv.y * zv.y + wv.z * zv.z + wv.w * zv.w;
    }
    ws[WS_Y + b * 128 + tx] = s;
  }
}

// ---------------- main step kernel: 64 candidates of one b ----------------
// 256 threads = 4 waves. lane (0..63) = candidate row; wid (0..3) = col block.
// LDS: Z[64][128] (32KB) + Hb[64][64] (16KB) = 48KB -> 3 WGs/CU.
// GEMM1: wave wid computes H cols hb*64 + wid*16 + (0..15) for all 64 rows.
// GEMM2: wave wid accumulates output cols wid*32 + (0..31), K blocked by hb.
__global__ __launch_bounds__(256, 3) void k_step(const float* __restrict__ W1g,
    const float* __restrict__ W2g, float* __restrict__ ws, int m)
{
  __shared__ float Z[8192];
  __shared__ float Hb[4096];
  int tx = threadIdx.x;
  int lane = tx & 63, wid = tx >> 6;
  int b = blockIdx.x >> 2, t = blockIdx.x & 3, k0 = t << 6;
  int rot = (lane & 7) << 2;

  // init Z = zc[k0+r] + y[b]  (rotated store)
  {
    const float* zc = ws + WS_ZC + k0 * 128;
    const float* y  = ws + WS_Y + b * 128;
    for (int i = tx; i < 2048; i += 256) {
      int r = i >> 5, dq = (i & 31) << 2;
      float4 zv = *(const float4*)(zc + r * 128 + dq);
      float4 yv = *(const float4*)(y + dq);
      zv.x += yv.x; zv.y += yv.y; zv.z += yv.z; zv.w += yv.w;
      *(float4*)(Z + rotZ(r, dq)) = zv;
    }
  }
  __syncthreads();

  for (int l = 0; l < 2; l++) {
    float accz[32];
#pragma unroll
    for (int q = 0; q < 32; q++) accz[q] = 0.f;
    const float* w1l = W1g + (size_t)(m * 2 + l) * (256 * 128);
    const float* w2l = W2g + (size_t)(m * 2 + l) * (128 * 256);

    for (int hb = 0; hb < 4; hb++) {
      // ---- GEMM1: a1[c] = relu-pending sum_d Z[lane][d] * W1[hb*64+wid*16+c][d]
      float a1[16];
#pragma unroll
      for (int c = 0; c < 16; c++) a1[c] = 0.f;
      const float* w1b = w1l + (hb * 64 + wid * 16) * 128;
      for (int d = 0; d < 128; d += 4) {
        float4 zv = *(const float4*)(Z + (lane << 7) + ((d + rot) & 127));
#pragma unroll
        for (int c = 0; c < 16; c++) {
          float4 wv = *(const float4*)(w1b + c * 128 + d);   // lane-invariant (broadcast)
          a1[c] = fmaf(zv.w, wv.w, fmaf(zv.z, wv.z, fmaf(zv.y, wv.y, fmaf(zv.x, wv.x, a1[c]))));
        }
      }
      // relu + write Hb[lane][wid*16 + 0..15] (rotated, thread-exclusive)
#pragma unroll
      for (int j = 0; j < 4; j++) {
        float4 hv;
        hv.x = fmaxf(a1[4 * j + 0], 0.f);
        hv.y = fmaxf(a1[4 * j + 1], 0.f);
        hv.z = fmaxf(a1[4 * j + 2], 0.f);
        hv.w = fmaxf(a1[4 * j + 3], 0.f);
        *(float4*)(Hb + (lane << 6) + (((wid << 4) + (j << 2) + rot) & 63)) = hv;
      }
      __syncthreads();
      // ---- GEMM2 partial: accz[q] += sum_h Hb[lane][h] * W2[wid*32+q][hb*64+h]
      const float* w2b = w2l + (size_t)(wid * 32) * 256 + hb * 64;
      for (int h = 0; h < 64; h += 4) {
        float4 hv = *(const float4*)(Hb + (lane << 6) + ((h + rot) & 63));
#pragma unroll
        for (int q = 0; q < 32; q++) {
          float4 wv = *(const float4*)(w2b + q * 256 + h);   // lane-invariant (broadcast)
          accz[q] = fmaf(hv.w, wv.w, fmaf(hv.z, wv.z, fmaf(hv.y, wv.y, fmaf(hv.x, wv.x, accz[q]))));
        }
      }
      __syncthreads();
    }
    // Z[lane][wid*32 + 0..31] += accz (rotated RMW, thread-exclusive)
#pragma unroll
    for (int j = 0; j < 8; j++) {
      float4* pz = (float4*)(Z + (lane << 7) + (((wid << 5) + (j << 2) + rot) & 127));
      float4 z = *pz;
      z.x += accz[4 * j + 0]; z.y += accz[4 * j + 1];
      z.z += accz[4 * j + 2]; z.w += accz[4 * j + 3];
      *pz = z;
    }
    __syncthreads();
  }

  // ---- dist = ||rb - z||^2, argmin over 64 rows ----
  float* pd  = Hb;            // Hb free now
  int* rwin  = (int*)(Hb + 64);
  {
    const float* rb = ws + WS_RB + b * 128;
    int r = tx >> 2, qt = tx & 3;
    int dbase = qt << 5;
    int rrot = (r & 7) << 2;
    float s = 0.f;
    for (int d = 0; d < 32; d += 4) {
      int col = (dbase + d + rrot) & 127;
      float4 zv = *(const float4*)(Z + (r << 7) + col);
      float4 rv = *(const float4*)(rb + dbase + d);
      float a0 = rv.x - zv.x, a1 = rv.y - zv.y, a2 = rv.z - zv.z, a3 = rv.w - zv.w;
      s += a0 * a0 + a1 * a1 + a2 * a2 + a3 * a3;
    }
    s += __shfl_xor(s, 1);    // commutative adds: all 4 lanes bit-identical
    s += __shfl_xor(s, 2);
    if (qt == 0) pd[r] = s;
  }
  __syncthreads();
  if (tx < 64) {
    float v = pd[tx]; int idx = tx;
#pragma unroll
    for (int off = 32; off; off >>= 1) {
      float v2 = __shfl_xor(v, off);
      int   i2 = __shfl_xor(idx, off);
      if (v2 < v || (v2 == v && i2 < idx)) { v = v2; idx = i2; }
    }
    if (tx == 0) {
      ws[WS_BESTD + (b << 2) + t] = v;
      ((int*)ws)[WS_BESTI + (b << 2) + t] = k0 + idx;
      rwin[0] = idx;
    }
  }
  __syncthreads();
  if (tx < 32) {
    int rw = rwin[0];
    int col = ((tx << 2) + ((rw & 7) << 2)) & 127;
    *(float4*)(ws + WS_BESTZ + (((b << 2) + t) << 7) + (tx << 2)) =
        *(const float4*)(Z + (rw << 7) + col);
  }
}

// ---------------- per-step update: pick tile winner, advance xhat ----------------
__global__ __launch_bounds__(128) void k_update(const float* __restrict__ x,
    float* __restrict__ ws, float* __restrict__ out, int m, int last)
{
  __shared__ int tsel;
  int tx = threadIdx.x, b = blockIdx.x;
  if (tx == 0) {
    float bv = ws[WS_BESTD + (b << 2)]; int bt = 0;
    for (int q = 1; q < 4; q++) {
      float v = ws[WS_BESTD + (b << 2) + q];
      if (v < bv) { bv = v; bt = q; }     // strict <: ties -> lowest k (tile order)
    }
    tsel = bt;
    int k = ((const int*)ws)[WS_BESTI + (b << 2) + bt];
    out[OUT_CODES + b * 8 + (m + 1)] = (float)k;
  }
  __syncthreads();
  int bt = tsel;
  float z  = ws[WS_BESTZ + (((b << 2) + bt) << 7) + tx];
  float xh = ws[WS_XHAT + b * 128 + tx] + z;
  ws[WS_XHAT + b * 128 + tx] = xh;
  ws[WS_RB   + b * 128 + tx] = x[b * 128 + tx] - xh;
  out[OUT_SIDE + (m + 1) * 131072 + b * 128 + tx] = xh;
  if (last) out[b * 128 + tx] = xh;       // final xhat == side[7]
}

extern "C" void kernel_launch(void* const* d_in, const int* in_sizes, int n_in,
                              void* d_out, int out_size, void* d_ws, size_t ws_size,
                              hipStream_t stream)
{
  const float* x   = (const float*)d_in[0];
  const float* cb0 = (const float*)d_in[1];
  const float* cbs = (const float*)d_in[2];
  const float* Wc  = (const float*)d_in[3];
  const float* bc  = (const float*)d_in[4];
  const float* W1  = (const float*)d_in[5];
  const float* W2  = (const float*)d_in[6];
  float* out = (float*)d_out;
  float* ws  = (float*)d_ws;

  k_step0<<<1024, 256, 0, stream>>>(x, cb0, ws, out);
  for (int m = 0; m < 7; m++) {
    k_prep<<<1280, 128, 0, stream>>>(cbs + m * 256 * 128, Wc + m * 128 * 256,
                                     bc + m * 128, ws);
    k_step<<<4096, 256, 0, stream>>>(W1, W2, ws, m);
    k_update<<<1024, 128, 0, stream>>>(x, ws, out, m, (m == 6) ? 1 : 0);
  }
}

// Round 5
// 12888.950 us; speedup vs baseline: 1.9868x; 1.9868x over previous
//
#include <hip/hip_runtime.h>

// QINCo fp32, round 5: round-3 structure reworked.
//  - 2 rows (stride 32) x 8/16 cols per thread: LDS reads halved, and rows
//    rg / rg+32 are read by lanes L / L+32 at the same address (broadcast).
//  - Padded LDS (Z[64][132], Hb[64][68]) instead of rotation: conflict-free
//    banks with zero per-iteration address VALU (immediate offsets).
//  - Weights stay per-thread-distinct global loads (round 3 proven).
// Shapes: D=128, M=8, K=256, L=2, H=256, BS=1024. All fp32.
// Out layout (floats): xhat[1024*128] | codes[1024*8] | side[8][1024*128]

#define OUT_CODES 131072
#define OUT_SIDE  139264

// ws float offsets
#define WS_XHAT  0          // [1024][128]
#define WS_RB    131072     // [1024][128]  r = x - xhat
#define WS_Y     262144     // [1024][128]  y = xhat @ Wx^T
#define WS_ZC    393216     // [256][128]   zc = cb + cb@Wz^T + bc
#define WS_BESTD 425984     // [1024][4]
#define WS_BESTI 430080     // [1024][4] (int)
#define WS_BESTZ 434176     // [1024][4][128]

#define ZP 132              // padded Z row stride (floats)
#define HP 68               // padded Hb row stride (floats)

// ---------------- step 0: nearest codebook0 row ----------------
__global__ __launch_bounds__(256) void k_step0(const float* __restrict__ x,
    const float* __restrict__ cb0, float* __restrict__ ws, float* __restrict__ out)
{
  __shared__ float xs[128];
  __shared__ float redv[4];
  __shared__ int   redi[4];
  __shared__ int   kwin;
  int tx = threadIdx.x, b = blockIdx.x;
  if (tx < 128) xs[tx] = x[b * 128 + tx];
  __syncthreads();
  const float* c = cb0 + tx * 128;   // k = tx
  float s = 0.f;
  for (int d = 0; d < 128; d += 4) {
    float4 cv = *(const float4*)(c + d);
    float4 xv = *(const float4*)(xs + d);
    float a0 = xv.x - cv.x, a1 = xv.y - cv.y, a2 = xv.z - cv.z, a3 = xv.w - cv.w;
    s += a0 * a0 + a1 * a1 + a2 * a2 + a3 * a3;
  }
  float v = s; int idx = tx;
  for (int off = 32; off; off >>= 1) {
    float v2 = __shfl_xor(v, off);
    int   i2 = __shfl_xor(idx, off);
    if (v2 < v || (v2 == v && i2 < idx)) { v = v2; idx = i2; }
  }
  if ((tx & 63) == 0) { redv[tx >> 6] = v; redi[tx >> 6] = idx; }
  __syncthreads();
  if (tx == 0) {
    float bv = redv[0]; int bi = redi[0];
    for (int w = 1; w < 4; w++)
      if (redv[w] < bv || (redv[w] == bv && redi[w] < bi)) { bv = redv[w]; bi = redi[w]; }
    kwin = bi;
    out[OUT_CODES + b * 8] = (float)bi;
  }
  __syncthreads();
  int k = kwin;
  if (tx < 128) {
    float xh = cb0[k * 128 + tx];
    ws[WS_XHAT + b * 128 + tx] = xh;
    ws[WS_RB   + b * 128 + tx] = xs[tx] - xh;
    out[OUT_SIDE + b * 128 + tx] = xh;   // side[0]
  }
}

// ---------------- per-step prep: zc and y ----------------
__global__ __launch_bounds__(128) void k_prep(const float* __restrict__ cb,
    const float* __restrict__ Wc, const float* __restrict__ bcm, float* __restrict__ ws)
{
  __shared__ float row[128];
  int tx = threadIdx.x, blk = blockIdx.x;
  if (blk < 256) {          // zc[k][i] = cb[k][i] + sum_d cb[k][d]*Wc[i][d] + bc[i]
    row[tx] = cb[blk * 128 + tx];
    __syncthreads();
    const float* wrow = Wc + tx * 256;
    float s = 0.f;
    for (int d = 0; d < 128; d += 4) {
      float4 wv = *(const float4*)(wrow + d);
      float4 zv = *(const float4*)(row + d);
      s += wv.x * zv.x + wv.y * zv.y + wv.z * zv.z + wv.w * zv.w;
    }
    ws[WS_ZC + blk * 128 + tx] = row[tx] + s + bcm[tx];
  } else {                  // y[b][i] = sum_d xhat[b][d]*Wc[i][128+d]
    int b = blk - 256;
    row[tx] = ws[WS_XHAT + b * 128 + tx];
    __syncthreads();
    const float* wrow = Wc + tx * 256 + 128;
    float s = 0.f;
    for (int d = 0; d < 128; d += 4) {
      float4 wv = *(const float4*)(wrow + d);
      float4 zv = *(const float4*)(row + d);
      s += wv.x * zv.x + wv.y * zv.y + wv.z * zv.z + wv.w * zv.w;
    }
    ws[WS_Y + b * 128 + tx] = s;
  }
}

// ---------------- main step kernel: 64 candidates of one b ----------------
// 256 threads = 4 waves. rg = tx&31 (rows rg, rg+32), cg = tx>>5 (0..7).
// LDS: Z[64][132] + Hb[64][68] = 50KB -> 3 WGs/CU.
// GEMM1 (per hb, 64 H-cols): thread cols 8cg..8cg+7, a1[2][8].
// GEMM2 (out 128 cols):      thread cols 16cg..16cg+15, accz[2][16].
__global__ __launch_bounds__(256, 3) void k_step(const float* __restrict__ W1g,
    const float* __restrict__ W2g, float* __restrict__ ws, int m)
{
  __shared__ float Z[64 * ZP];
  __shared__ float Hb[64 * HP];
  int tx = threadIdx.x;
  int rg = tx & 31, cg = tx >> 5;
  int b = blockIdx.x >> 2, t = blockIdx.x & 3, k0 = t << 6;

  // init Z = zc[k0+r] + y[b]
  {
    const float* zc = ws + WS_ZC + k0 * 128;
    const float* y  = ws + WS_Y + b * 128;
    for (int i = tx; i < 2048; i += 256) {
      int r = i >> 5, dq = (i & 31) << 2;
      float4 zv = *(const float4*)(zc + r * 128 + dq);
      float4 yv = *(const float4*)(y + dq);
      zv.x += yv.x; zv.y += yv.y; zv.z += yv.z; zv.w += yv.w;
      *(float4*)(Z + r * ZP + dq) = zv;
    }
  }
  __syncthreads();

  const float* Zr0 = Z + rg * ZP;           // row rg
  const float* Zr1 = Z + (rg + 32) * ZP;    // row rg+32
  float* Hw0 = Hb + rg * HP + (cg << 3);
  float* Hw1 = Hb + (rg + 32) * HP + (cg << 3);
  const float* Hr0 = Hb + rg * HP;
  const float* Hr1 = Hb + (rg + 32) * HP;

  for (int l = 0; l < 2; l++) {
    const float* w1l = W1g + (size_t)(m * 2 + l) * (256 * 128);
    const float* w2l = W2g + (size_t)(m * 2 + l) * (128 * 256);
    float accz[2][16];
#pragma unroll
    for (int i = 0; i < 2; i++)
#pragma unroll
      for (int q = 0; q < 16; q++) accz[i][q] = 0.f;

    for (int hb = 0; hb < 4; hb++) {
      // ---- GEMM1: a1[i][c] = sum_d Z[row_i][d] * W1[hb*64+8cg+c][d] ----
      float a1[2][8];
#pragma unroll
      for (int i = 0; i < 2; i++)
#pragma unroll
        for (int c = 0; c < 8; c++) a1[i][c] = 0.f;
      const float* w1b = w1l + (size_t)(hb * 64 + (cg << 3)) * 128;
      for (int d = 0; d < 128; d += 4) {
        float4 z0 = *(const float4*)(Zr0 + d);   // lanes L / L+32: same addr (broadcast)
        float4 z1 = *(const float4*)(Zr1 + d);
#pragma unroll
        for (int c = 0; c < 8; c++) {
          float4 wv = *(const float4*)(w1b + c * 128 + d);
          a1[0][c] = fmaf(z0.w, wv.w, fmaf(z0.z, wv.z, fmaf(z0.y, wv.y, fmaf(z0.x, wv.x, a1[0][c]))));
          a1[1][c] = fmaf(z1.w, wv.w, fmaf(z1.z, wv.z, fmaf(z1.y, wv.y, fmaf(z1.x, wv.x, a1[1][c]))));
        }
      }
      // relu + store Hb
#pragma unroll
      for (int j = 0; j < 2; j++) {
        float4 h0, h1;
        h0.x = fmaxf(a1[0][4 * j + 0], 0.f); h0.y = fmaxf(a1[0][4 * j + 1], 0.f);
        h0.z = fmaxf(a1[0][4 * j + 2], 0.f); h0.w = fmaxf(a1[0][4 * j + 3], 0.f);
        h1.x = fmaxf(a1[1][4 * j + 0], 0.f); h1.y = fmaxf(a1[1][4 * j + 1], 0.f);
        h1.z = fmaxf(a1[1][4 * j + 2], 0.f); h1.w = fmaxf(a1[1][4 * j + 3], 0.f);
        *(float4*)(Hw0 + 4 * j) = h0;
        *(float4*)(Hw1 + 4 * j) = h1;
      }
      __syncthreads();
      // ---- GEMM2 partial: accz[i][q] += sum_h Hb[row_i][h] * W2[16cg+q][hb*64+h] ----
      const float* w2b = w2l + (size_t)(cg << 4) * 256 + hb * 64;
      for (int h = 0; h < 64; h += 4) {
        float4 h0 = *(const float4*)(Hr0 + h);
        float4 h1 = *(const float4*)(Hr1 + h);
#pragma unroll
        for (int q = 0; q < 16; q++) {
          float4 wv = *(const float4*)(w2b + q * 256 + h);
          accz[0][q] = fmaf(h0.w, wv.w, fmaf(h0.z, wv.z, fmaf(h0.y, wv.y, fmaf(h0.x, wv.x, accz[0][q]))));
          accz[1][q] = fmaf(h1.w, wv.w, fmaf(h1.z, wv.z, fmaf(h1.y, wv.y, fmaf(h1.x, wv.x, accz[1][q]))));
        }
      }
      __syncthreads();
    }
    // Z[row_i][16cg + 0..15] += accz (thread-exclusive)
#pragma unroll
    for (int i = 0; i < 2; i++) {
      float* zr = Z + (rg + 32 * i) * ZP + (cg << 4);
#pragma unroll
      for (int j = 0; j < 4; j++) {
        float4* pz = (float4*)(zr + 4 * j);
        float4 z = *pz;
        z.x += accz[i][4 * j + 0]; z.y += accz[i][4 * j + 1];
        z.z += accz[i][4 * j + 2]; z.w += accz[i][4 * j + 3];
        *pz = z;
      }
    }
    __syncthreads();
  }

  // ---- dist = ||rb - z||^2 : wave w sums d-range [32w, 32w+32) for all rows ----
  float* pd = Hb;              // Hb free now: pd[4][64]
  int* rwin = (int*)(Hb + 256);
  {
    int lane = tx & 63, w = tx >> 6;
    const float* rb = ws + WS_RB + b * 128 + (w << 5);
    const float* zrow = Z + lane * ZP + (w << 5);
    float s = 0.f;
    for (int d = 0; d < 32; d += 4) {
      float4 zv = *(const float4*)(zrow + d);
      float4 rv = *(const float4*)(rb + d);
      float a0 = rv.x - zv.x, a1 = rv.y - zv.y, a2 = rv.z - zv.z, a3 = rv.w - zv.w;
      s += a0 * a0 + a1 * a1 + a2 * a2 + a3 * a3;
    }
    pd[(w << 6) + lane] = s;
  }
  __syncthreads();
  if (tx < 64) {
    float v = ((pd[tx] + pd[64 + tx]) + pd[128 + tx]) + pd[192 + tx];
    int idx = tx;
#pragma unroll
    for (int off = 32; off; off >>= 1) {
      float v2 = __shfl_xor(v, off);
      int   i2 = __shfl_xor(idx, off);
      if (v2 < v || (v2 == v && i2 < idx)) { v = v2; idx = i2; }
    }
    if (tx == 0) {
      ws[WS_BESTD + (b << 2) + t] = v;
      ((int*)ws)[WS_BESTI + (b << 2) + t] = k0 + idx;
      rwin[0] = idx;
    }
  }
  __syncthreads();
  if (tx < 32) {
    int rw = rwin[0];
    *(float4*)(ws + WS_BESTZ + (((b << 2) + t) << 7) + (tx << 2)) =
        *(const float4*)(Z + rw * ZP + (tx << 2));
  }
}

// ---------------- per-step update: pick tile winner, advance xhat ----------------
__global__ __launch_bounds__(128) void k_update(const float* __restrict__ x,
    float* __restrict__ ws, float* __restrict__ out, int m, int last)
{
  __shared__ int tsel;
  int tx = threadIdx.x, b = blockIdx.x;
  if (tx == 0) {
    float bv = ws[WS_BESTD + (b << 2)]; int bt = 0;
    for (int q = 1; q < 4; q++) {
      float v = ws[WS_BESTD + (b << 2) + q];
      if (v < bv) { bv = v; bt = q; }     // strict <: ties -> lowest k (tile order)
    }
    tsel = bt;
    int k = ((const int*)ws)[WS_BESTI + (b << 2) + bt];
    out[OUT_CODES + b * 8 + (m + 1)] = (float)k;
  }
  __syncthreads();
  int bt = tsel;
  float z  = ws[WS_BESTZ + (((b << 2) + bt) << 7) + tx];
  float xh = ws[WS_XHAT + b * 128 + tx] + z;
  ws[WS_XHAT + b * 128 + tx] = xh;
  ws[WS_RB   + b * 128 + tx] = x[b * 128 + tx] - xh;
  out[OUT_SIDE + (m + 1) * 131072 + b * 128 + tx] = xh;
  if (last) out[b * 128 + tx] = xh;       // final xhat == side[7]
}

extern "C" void kernel_launch(void* const* d_in, const int* in_sizes, int n_in,
                              void* d_out, int out_size, void* d_ws, size_t ws_size,
                              hipStream_t stream)
{
  const float* x   = (const float*)d_in[0];
  const float* cb0 = (const float*)d_in[1];
  const float* cbs = (const float*)d_in[2];
  const float* Wc  = (const float*)d_in[3];
  const float* bc  = (const float*)d_in[4];
  const float* W1  = (const float*)d_in[5];
  const float* W2  = (const float*)d_in[6];
  float* out = (float*)d_out;
  float* ws  = (float*)d_ws;

  k_step0<<<1024, 256, 0, stream>>>(x, cb0, ws, out);
  for (int m = 0; m < 7; m++) {
    k_prep<<<1280, 128, 0, stream>>>(cbs + m * 256 * 128, Wc + m * 128 * 256,
                                     bc + m * 128, ws);
    k_step<<<4096, 256, 0, stream>>>(W1, W2, ws, m);
    k_update<<<1024, 128, 0, stream>>>(x, ws, out, m, (m == 6) ? 1 : 0);
  }
}